// Round 20
// baseline (282.731 us; speedup 1.0000x reference)
//
#include <hip/hip_runtime.h>
#include <math.h>

#define H_IMG 1080
#define W_IMG 1920
#define NPIX (H_IMG * W_IMG)
#define NB_NM 8100                             // NPIX / 256 (k_nm grid, 1 px/thread)
#define RB_REAL 2025                           // k_resid blocks (256 thr x 4 px = 1024 px/blk)
#define NACC 27

// ---- workspace layout (byte offsets) ----
#define OFF_POSE     0                         // 16 f32
#define OFF_MINMAX   64                        // 2 u32
#define OFF_COUNT    128                       // 1 u32 ticket
#define OFF_SUMS     192                       // NACC f64
#define OFF_PARTIALS 1024                      // NACC * RB_REAL f32 = 218700 B
#define OFF_ND       524288                    // NPIX f16x4 {d,nx,ny,nz} = 16.6 MB

typedef _Float16 h4 __attribute__((ext_vector_type(4)));
typedef _Float16 h8 __attribute__((ext_vector_type(8)));

// 27 accumulators as NAMED scalars (index, name).
#define ACC_LIST(X) \
    X(0,s00) X(1,s01) X(2,s02) X(3,s03) X(4,s04) X(5,s05) \
    X(6,s11) X(7,s12) X(8,s13) X(9,s14) X(10,s15) \
    X(11,s22) X(12,s23) X(13,s24) X(14,s25) \
    X(15,s33) X(16,s34) X(17,s35) \
    X(18,s44) X(19,s45) X(20,s55) \
    X(21,b0) X(22,b1) X(23,b2) X(24,b3) X(25,b4) X(26,b5)

// bijective XCD-chunking swizzle
__device__ __forceinline__ int swz_bid(int orig, int nwg) {
    int q = nwg >> 3, r = nwg & 7;
    int xcd = orig & 7, lid = orig >> 3;
    return (xcd < r) ? xcd * (q + 1) + lid : r * (q + 1) + (xcd - r) * q + lid;
}

__global__ void k_init(const float* __restrict__ pose_in, float* __restrict__ ws_pose,
                       unsigned int* __restrict__ minmax, unsigned int* __restrict__ counter) {
    int t = threadIdx.x;
    if (t < 16) ws_pose[t] = pose_in[t];
    if (t == 16) { minmax[0] = 0x7F800000u; minmax[1] = 0u; }
    if (t == 17) *counter = 0u;
}

// 1 px/thread: UNMASKED normal + depth packed as f16x4 {d,nx,ny,nz} -> 8 B/px.
// Also computes the global depth1 min/max (block reduce + 2 atomics) so the
// separate k_minmax dispatch is gone; the invalid mask is applied in k_resid.
__global__ __launch_bounds__(256)
void k_nm(const float* __restrict__ depth1, const float* __restrict__ Kmat,
          h4* __restrict__ nd, unsigned int* __restrict__ minmax) {
    float fx = Kmat[0], cx = Kmat[2], fy = Kmat[4], cy = Kmat[5];
    float ifx = 1.f / fx, ify = 1.f / fy;
    int idx = blockIdx.x * 256 + threadIdx.x;  // grid exactly NB_NM*256 == NPIX
    int j = idx / W_IMG;
    int i = idx - j * W_IMG;
    int r0 = j > 0 ? j - 1 : 0;
    int r2 = j < H_IMG - 1 ? j + 1 : H_IMG - 1;
    int il = i > 0 ? i - 1 : 0;
    int ir = i < W_IMG - 1 ? i + 1 : W_IMG - 1;
    const float* rp0 = depth1 + (size_t)r0 * W_IMG;
    const float* rp1 = depth1 + (size_t)j * W_IMG;
    const float* rp2 = depth1 + (size_t)r2 * W_IMG;
    float d00 = rp0[il], d01 = rp0[i], d02 = rp0[ir];
    float d10 = rp1[il], d11 = rp1[i], d12 = rp1[ir];
    float d20 = rp2[il], d21 = rp2[i], d22 = rp2[ir];
    float c0 = ((float)il - cx) * ifx, c1 = ((float)i - cx) * ifx, c2 = ((float)ir - cx) * ifx;
    float w0 = ((float)r0 - cy) * ify, w1 = ((float)j - cy) * ify, w2 = ((float)r2 - cy) * ify;
    float dxx = -c0 * d00 + c2 * d02 - 2.f * (c0 * d10) + 2.f * (c2 * d12) - c0 * d20 + c2 * d22;
    float dxy = -w0 * d00 + w0 * d02 - 2.f * (w1 * d10) + 2.f * (w1 * d12) - w2 * d20 + w2 * d22;
    float dxz = -d00 + d02 - 2.f * d10 + 2.f * d12 - d20 + d22;
    float dyx = -c0 * d00 - 2.f * (c1 * d01) - c2 * d02 + c0 * d20 + 2.f * (c1 * d21) + c2 * d22;
    float dyy = -w0 * d00 - 2.f * (w0 * d01) - w0 * d02 + w2 * d20 + 2.f * (w2 * d21) + w2 * d22;
    float dyz = -d00 - 2.f * d01 - d02 + d20 + 2.f * d21 + d22;
    float nx = dxy * dyz - dxz * dyy;
    float ny = dxz * dyx - dxx * dyz;
    float nz = dxx * dyy - dxy * dyx;
    float inv = 1.f / (sqrtf(nx * nx + ny * ny + nz * nz) + 1e-8f);
    h4 e;
    e[0] = (_Float16)d11;
    e[1] = (_Float16)(nx * inv);
    e[2] = (_Float16)(ny * inv);
    e[3] = (_Float16)(nz * inv);
    nd[idx] = e;

    // global depth1 min/max (each pixel counted exactly once)
    float mn = d11, mx = d11;
    for (int off = 32; off > 0; off >>= 1) {
        mn = fminf(mn, __shfl_down(mn, off));
        mx = fmaxf(mx, __shfl_down(mx, off));
    }
    __shared__ float smn[4], smx[4];
    int lane = threadIdx.x & 63, wid = threadIdx.x >> 6;
    if (lane == 0) { smn[wid] = mn; smx[wid] = mx; }
    __syncthreads();
    if (threadIdx.x == 0) {
        for (int w = 1; w < 4; w++) { mn = fminf(mn, smn[w]); mx = fmaxf(mx, smx[w]); }
        atomicMin(&minmax[0], __float_as_uint(mn));  // positive floats: bit order == value order
        atomicMax(&minmax[1], __float_as_uint(mx));
    }
}

// resid: 4 px/thread, 8 gathers (2x16B per px) issued back-to-back; per-corner
// invalid mask (f16 depth vs exact f32 dmin/dmax, R4-proven) via packed multiply.
__global__ __launch_bounds__(256, 4)
void k_resid(const float* __restrict__ depth0, const float* __restrict__ Kmat,
             const h4* __restrict__ nd, const unsigned int* __restrict__ minmax,
             const float* __restrict__ pose, float* __restrict__ partials) {
    float fx = Kmat[0], cx = Kmat[2], fy = Kmat[4], cy = Kmat[5];
    float ifx = 1.f / fx, ify = 1.f / fy;
    float R00 = pose[0], R01 = pose[1], R02 = pose[2],  t0 = pose[3];
    float R10 = pose[4], R11 = pose[5], R12 = pose[6],  t1 = pose[7];
    float R20 = pose[8], R21 = pose[9], R22 = pose[10], t2 = pose[11];
    float dmin = __uint_as_float(minmax[0]);
    float dmax = __uint_as_float(minmax[1]);

#define ACC_DECL(i, n) float n = 0.f;
    ACC_LIST(ACC_DECL)
#undef ACC_DECL

    int tid = threadIdx.x;
    int wg = swz_bid(blockIdx.x, gridDim.x);
    int base = wg * 1024;                      // grid*1024 == NPIX exactly

    float d0s[4];
#pragma unroll
    for (int p = 0; p < 4; p++) d0s[p] = depth0[base + p * 256 + tid];  // coalesced

    float px[4], py[4], pz[4], wx[4], wy[4];
    int x0[4], y0[4];
    bool inview[4];
#pragma unroll
    for (int p = 0; p < 4; p++) {
        int idx = base + p * 256 + tid;
        int j = idx / W_IMG;
        int i = idx - j * W_IMG;
        float d0 = d0s[p];
        float cX = ((float)i - cx) * ifx;
        float cY = ((float)j - cy) * ify;
        float ax = R00 * cX + R01 * cY + R02;
        float ay = R10 * cX + R11 * cY + R12;
        float az = R20 * cX + R21 * cY + R22;
        float X = ax * d0 + t0;
        float Y = ay * d0 + t1;
        float Z = az * d0 + t2;
        float u, v; bool iv;
        if (Z > 1e-6f) {
            float rz = __builtin_amdgcn_rcpf(Z);
            u = X * rz * fx + cx;
            v = Y * rz * fy + cy;
            iv = (u > 0.f) && (u < (float)(W_IMG - 1)) && (v > 0.f) && (v < (float)(H_IMG - 1));
        } else { u = 0.f; v = 0.f; iv = false; }
        float x0f = floorf(u), y0f = floorf(v);
        x0[p] = (int)x0f; y0[p] = (int)y0f;
        wx[p] = u - x0f; wy[p] = v - y0f;
        px[p] = X; py[p] = Y; pz[p] = Z; inview[p] = iv;
    }
    // 8 gathers of 16 B, all independent, issued together
    h8 T[4], B[4];
    const h8 zz = {(_Float16)0.f, (_Float16)0.f, (_Float16)0.f, (_Float16)0.f,
                   (_Float16)0.f, (_Float16)0.f, (_Float16)0.f, (_Float16)0.f};
#pragma unroll
    for (int p = 0; p < 4; p++) {
        if (inview[p]) {
            size_t b00 = (size_t)(y0[p] * W_IMG + x0[p]);
            T[p] = *reinterpret_cast<const h8*>(nd + b00);          // row y0: rec(x0), rec(x0+1)
            B[p] = *reinterpret_cast<const h8*>(nd + b00 + W_IMG);  // row y0+1
        } else { T[p] = zz; B[p] = zz; }
    }
#pragma unroll
    for (int p = 0; p < 4; p++) {
        float d00 = (float)T[p][0], d01 = (float)T[p][4];
        float d10 = (float)B[p][0], d11 = (float)B[p][4];
        // per-corner invalid mask (zero normal at global depth min/max)
        const _Float16 one = (_Float16)1.f, nil = (_Float16)0.f;
        _Float16 m00 = ((d00 <= dmin) || (d00 >= dmax)) ? nil : one;
        _Float16 m01 = ((d01 <= dmin) || (d01 >= dmax)) ? nil : one;
        _Float16 m10 = ((d10 <= dmin) || (d10 >= dmax)) ? nil : one;
        _Float16 m11 = ((d11 <= dmin) || (d11 >= dmax)) ? nil : one;
        h8 mT = {one, m00, m00, m00, one, m01, m01, m01};
        h8 mB = {one, m10, m10, m10, one, m11, m11, m11};
        _Float16 hy = (_Float16)wy[p], h1y = (_Float16)(1.f - wy[p]);
        h8 vwy = {hy, hy, hy, hy, hy, hy, hy, hy};
        h8 v1y = {h1y, h1y, h1y, h1y, h1y, h1y, h1y, h1y};
        h8 V = (T[p] * mT) * v1y + (B[p] * mB) * vwy;  // {dv0,nx0,ny0,nz0, dv1,nx1,ny1,nz1}
        float w1x = 1.f - wx[p];
        float rvz = d00 * (1.f - wy[p]) * w1x + d01 * (1.f - wy[p]) * wx[p]
                  + d10 * wy[p] * w1x + d11 * wy[p] * wx[p];
        float rnx = (float)V[1] * w1x + (float)V[5] * wx[p];
        float rny = (float)V[2] * w1x + (float)V[6] * wx[p];
        float rnz = (float)V[3] * w1x + (float)V[7] * wx[p];
        float cX0 = ((float)x0[p] - cx) * ifx;
        float cY0 = ((float)y0[p] - cy) * ify;
        float dv0 = (float)V[0], dv1 = (float)V[4];   // lane0 mask==1: pure vertical depth lerp
        float rvx = cX0 * dv0 * w1x + (cX0 + ifx) * dv1 * wx[p];
        float dY0 = cY0 * (1.f - wy[p]), dY1 = (cY0 + ify) * wy[p];
        float rvy = (dY0 * d00 + dY1 * d10) * w1x + (dY0 * d01 + dY1 * d11) * wx[p];
        bool mask1 = rvz > 0.f;
        float ddx = px[p] - rvx, ddy = py[p] - rvy, ddz = pz[p] - rvz;
        float n2 = ddx * ddx + ddy * ddy + ddz * ddz;
        bool occ = (!inview[p]) || (n2 > 0.01f);
        bool bad = occ || !(d0s[p] > 0.f) || (!mask1);
        if (!bad) {
            float r = rnx * ddx + rny * ddy + rnz * ddz;
            float j0 = -(py[p] * rnz - pz[p] * rny);
            float j1 = -(pz[p] * rnx - px[p] * rnz);
            float j2 = -(px[p] * rny - py[p] * rnx);
            float j3 = -rnx, j4 = -rny, j5 = -rnz;
            s00 += j0 * j0; s01 += j0 * j1; s02 += j0 * j2; s03 += j0 * j3; s04 += j0 * j4; s05 += j0 * j5;
            s11 += j1 * j1; s12 += j1 * j2; s13 += j1 * j3; s14 += j1 * j4; s15 += j1 * j5;
            s22 += j2 * j2; s23 += j2 * j3; s24 += j2 * j4; s25 += j2 * j5;
            s33 += j3 * j3; s34 += j3 * j4; s35 += j3 * j5;
            s44 += j4 * j4; s45 += j4 * j5;
            s55 += j5 * j5;
            b0 += j0 * r; b1 += j1 * r; b2 += j2 * r;
            b3 += j3 * r; b4 += j4 * r; b5 += j5 * r;
        }
    }

    __shared__ float red[NACC][64];
    __shared__ float part2[NACC][8];
#define ACC_RED(i, n) { float v = n; v += __shfl_xor(v, 1); v += __shfl_xor(v, 2); \
                        if ((tid & 3) == 0) red[i][tid >> 2] = v; }
    ACC_LIST(ACC_RED)
#undef ACC_RED
    __syncthreads();
    if (tid < NACC * 8) {
        int k = tid >> 3, seg = tid & 7;
        const float4* row = reinterpret_cast<const float4*>(&red[k][seg * 8]);
        float4 a = row[0], b = row[1];
        part2[k][seg] = (a.x + a.y + a.z + a.w) + (b.x + b.y + b.z + b.w);
    }
    __syncthreads();
    if (tid < NACC) {
        float s = 0.f;
#pragma unroll
        for (int m = 0; m < 8; m++) s += part2[tid][m];
        partials[(size_t)tid * RB_REAL + blockIdx.x] = s;
    }
}

// 27 blocks: reduce + last-block GN solve (series trig for small angles).
__global__ __launch_bounds__(256)
void k_reduce_solve(const float* __restrict__ partials, double* __restrict__ sums,
                    unsigned int* __restrict__ counter, float* __restrict__ pose,
                    float* __restrict__ pose_out) {
    int k = blockIdx.x;
    int tid = threadIdx.x;
    double v = 0.0;
    for (int i = tid; i < RB_REAL; i += 256) v += (double)partials[(size_t)k * RB_REAL + i];
    for (int off = 32; off > 0; off >>= 1) v += __shfl_down(v, off);
    __shared__ double sw[4];
    __shared__ int amLast;
    int lane = tid & 63, wid = tid >> 6;
    if (lane == 0) sw[wid] = v;
    __syncthreads();
    if (tid == 0) {
        sums[k] = sw[0] + sw[1] + sw[2] + sw[3];
        __threadfence();
        unsigned int old = atomicAdd(counter, 1u);
        amLast = (old == NACC - 1) ? 1 : 0;
    }
    __syncthreads();
    if (!amLast) return;
    __threadfence();

    if (tid == 0) {
        double ssum[NACC];
        for (int q = 0; q < NACC; q++) ssum[q] = sums[q];
        double sM[6][7];
        int kk = 0;
        for (int a = 0; a < 6; a++)
            for (int c = a; c < 6; c++) {
                double s = ssum[kk++];
                sM[a][c] = s; sM[c][a] = s;
            }
        double tr = sM[0][0] + sM[1][1] + sM[2][2] + sM[3][3] + sM[4][4] + sM[5][5];
        for (int a = 0; a < 6; a++) sM[a][a] += tr * 0.001;
        for (int a = 0; a < 6; a++) sM[a][6] = ssum[21 + a];
        for (int c = 0; c < 6; c++) {
            int piv = c;
            double best = fabs(sM[c][c]);
            for (int r = c + 1; r < 6; r++) {
                double vv = fabs(sM[r][c]);
                if (vv > best) { best = vv; piv = r; }
            }
            if (piv != c)
                for (int q = c; q < 7; q++) { double t = sM[c][q]; sM[c][q] = sM[piv][q]; sM[piv][q] = t; }
            double pv = sM[c][c];
            for (int r = 0; r < 6; r++) {
                if (r == c) continue;
                double f = sM[r][c] / pv;
                for (int q = c; q < 7; q++) sM[r][q] -= f * sM[c][q];
            }
        }
        double xi0 = sM[0][6] / sM[0][0], xi1 = sM[1][6] / sM[1][1], xi2 = sM[2][6] / sM[2][2];
        double xi3 = sM[3][6] / sM[3][3], xi4 = sM[4][6] / sM[4][4], xi5 = sM[5][6] / sM[5][5];
        double th2 = xi0 * xi0 + xi1 * xi1 + xi2 * xi2;
        double th = sqrt(th2);
        double dR[3][3] = {{1, 0, 0}, {0, 1, 0}, {0, 0, 1}};
        if (th > 1e-10) {
            double sA, sB;
            if (th < 0.5) {  // Taylor: rel err < 1e-7 at th=0.5; avoids f64 trig libcalls
                double t4 = th2 * th2, t6 = t4 * th2;
                sA = 1.0 - th2 / 6.0 + t4 / 120.0 - t6 / 5040.0;
                sB = 0.5 - th2 / 24.0 + t4 / 720.0 - t6 / 40320.0;
            } else {
                sA = sin(th) / th;
                sB = (1.0 - cos(th)) / th2;
            }
            double wh[3][3] = {{0, -xi2, xi1}, {xi2, 0, -xi0}, {-xi1, xi0, 0}};
#pragma unroll
            for (int r = 0; r < 3; r++)
#pragma unroll
                for (int cc = 0; cc < 3; cc++) {
                    double w2 = 0;
#pragma unroll
                    for (int m = 0; m < 3; m++) w2 += wh[r][m] * wh[m][cc];
                    dR[r][cc] = (r == cc ? 1.0 : 0.0) + sA * wh[r][cc] + sB * w2;
                }
        }
        double R[3][3], t[3];
#pragma unroll
        for (int r = 0; r < 3; r++) {
#pragma unroll
            for (int cc = 0; cc < 3; cc++) R[r][cc] = pose[r * 4 + cc];
            t[r] = pose[r * 4 + 3];
        }
        double xt[3] = {xi3, xi4, xi5};
#pragma unroll
        for (int r = 0; r < 3; r++) {
#pragma unroll
            for (int cc = 0; cc < 3; cc++) {
                double s = 0;
#pragma unroll
                for (int m = 0; m < 3; m++) s += dR[r][m] * R[m][cc];
                pose[r * 4 + cc] = (float)s;
            }
            pose[r * 4 + 3] = (float)(dR[r][0] * t[0] + dR[r][1] * t[1] + dR[r][2] * t[2] + xt[r]);
        }
        *counter = 0u;
        for (int q = 0; q < 16; q++) pose_out[q] = pose[q];
    }
}

extern "C" void kernel_launch(void* const* d_in, const int* in_sizes, int n_in,
                              void* d_out, int out_size, void* d_ws, size_t ws_size,
                              hipStream_t stream) {
    const float* pose_in = (const float*)d_in[0];
    const float* depth0 = (const float*)d_in[1];
    const float* depth1 = (const float*)d_in[2];
    const float* K = (const float*)d_in[3];
    float* out = (float*)d_out;
    char* ws = (char*)d_ws;
    float* ws_pose = (float*)(ws + OFF_POSE);
    unsigned int* minmax = (unsigned int*)(ws + OFF_MINMAX);
    unsigned int* counter = (unsigned int*)(ws + OFF_COUNT);
    double* sums = (double*)(ws + OFF_SUMS);
    float* partials = (float*)(ws + OFF_PARTIALS);
    h4* nd = (h4*)(ws + OFF_ND);

    k_init<<<1, 64, 0, stream>>>(pose_in, ws_pose, minmax, counter);
    k_nm<<<NB_NM, 256, 0, stream>>>(depth1, K, nd, minmax);
    for (int it = 0; it < 3; ++it) {
        k_resid<<<RB_REAL, 256, 0, stream>>>(depth0, K, nd, minmax, ws_pose, partials);
        k_reduce_solve<<<NACC, 256, 0, stream>>>(partials, sums, counter, ws_pose, out);
    }
}

// Round 21
// 110.341 us; speedup vs baseline: 2.5623x; 2.5623x over previous
//
#include <hip/hip_runtime.h>
#include <math.h>

#define H_IMG 1080
#define W_IMG 1920
#define NPIX (H_IMG * W_IMG)
#define QUADS (NPIX / 4)                       // 518400
#define NB_NM 8100                             // NPIX / 256 (k_nm grid, 1 px/thread)
#define RB_REAL 2025                           // k_resid blocks (256 thr x 4 px = 1024 px/blk)
#define NACC 27

// ---- workspace layout (byte offsets) ----
#define OFF_POSE     0                         // 16 f32
#define OFF_MINMAX   64                        // 2 u32
#define OFF_COUNT    128                       // 1 u32 ticket
#define OFF_SUMS     192                       // NACC f64
#define OFF_PARTIALS 1024                      // NACC * RB_REAL f32 = 218700 B
#define OFF_ND       524288                    // NPIX f16x4 {d,nx,ny,nz} = 16.6 MB

typedef _Float16 h4 __attribute__((ext_vector_type(4)));
typedef _Float16 h8 __attribute__((ext_vector_type(8)));

// 27 accumulators as NAMED scalars (index, name).
#define ACC_LIST(X) \
    X(0,s00) X(1,s01) X(2,s02) X(3,s03) X(4,s04) X(5,s05) \
    X(6,s11) X(7,s12) X(8,s13) X(9,s14) X(10,s15) \
    X(11,s22) X(12,s23) X(13,s24) X(14,s25) \
    X(15,s33) X(16,s34) X(17,s35) \
    X(18,s44) X(19,s45) X(20,s55) \
    X(21,b0) X(22,b1) X(23,b2) X(24,b3) X(25,b4) X(26,b5)

// bijective XCD-chunking swizzle
__device__ __forceinline__ int swz_bid(int orig, int nwg) {
    int q = nwg >> 3, r = nwg & 7;
    int xcd = orig & 7, lid = orig >> 3;
    return (xcd < r) ? xcd * (q + 1) + lid : r * (q + 1) + (xcd - r) * q + lid;
}

__global__ void k_init(const float* __restrict__ pose_in, float* __restrict__ ws_pose,
                       unsigned int* __restrict__ minmax, unsigned int* __restrict__ counter) {
    int t = threadIdx.x;
    if (t < 16) ws_pose[t] = pose_in[t];
    if (t == 16) { minmax[0] = 0x7F800000u; minmax[1] = 0u; }
    if (t == 17) *counter = 0u;
}

// 128 blocks only: same-address atomics serialize at ~28 cy each (R20: 16200
// atomics = 188 us). 256 atomics total ~= 3 us.
__global__ __launch_bounds__(256)
void k_minmax(const float4* __restrict__ dq, unsigned int* __restrict__ minmax) {
    int tid = blockIdx.x * blockDim.x + threadIdx.x;
    int stride = gridDim.x * blockDim.x;           // 128*256 = 32768; QUADS/32768 ~= 16 iters
    float mn = INFINITY, mx = -INFINITY;
    for (int i = tid; i < QUADS; i += stride) {
        float4 v = dq[i];
        mn = fminf(mn, fminf(fminf(v.x, v.y), fminf(v.z, v.w)));
        mx = fmaxf(mx, fmaxf(fmaxf(v.x, v.y), fmaxf(v.z, v.w)));
    }
    for (int off = 32; off > 0; off >>= 1) {
        mn = fminf(mn, __shfl_down(mn, off));
        mx = fmaxf(mx, __shfl_down(mx, off));
    }
    __shared__ float smn[4], smx[4];
    int lane = threadIdx.x & 63, wid = threadIdx.x >> 6;
    if (lane == 0) { smn[wid] = mn; smx[wid] = mx; }
    __syncthreads();
    if (threadIdx.x == 0) {
        for (int w = 1; w < 4; w++) { mn = fminf(mn, smn[w]); mx = fmaxf(mx, smx[w]); }
        atomicMin(&minmax[0], __float_as_uint(mn));  // positive floats: bit order == value order
        atomicMax(&minmax[1], __float_as_uint(mx));
    }
}

// 1 px/thread: masked normal + depth packed as f16x4 {d,nx,ny,nz} -> 8 B/px.
__global__ __launch_bounds__(256)
void k_nm(const float* __restrict__ depth1, const float* __restrict__ Kmat,
          const unsigned int* __restrict__ minmax, h4* __restrict__ nd) {
    float fx = Kmat[0], cx = Kmat[2], fy = Kmat[4], cy = Kmat[5];
    float ifx = 1.f / fx, ify = 1.f / fy;
    float dmin = __uint_as_float(minmax[0]), dmax = __uint_as_float(minmax[1]);
    int idx = blockIdx.x * 256 + threadIdx.x;  // grid exactly NB_NM*256 == NPIX
    int j = idx / W_IMG;
    int i = idx - j * W_IMG;
    int r0 = j > 0 ? j - 1 : 0;
    int r2 = j < H_IMG - 1 ? j + 1 : H_IMG - 1;
    int il = i > 0 ? i - 1 : 0;
    int ir = i < W_IMG - 1 ? i + 1 : W_IMG - 1;
    const float* rp0 = depth1 + (size_t)r0 * W_IMG;
    const float* rp1 = depth1 + (size_t)j * W_IMG;
    const float* rp2 = depth1 + (size_t)r2 * W_IMG;
    float d00 = rp0[il], d01 = rp0[i], d02 = rp0[ir];
    float d10 = rp1[il], d11 = rp1[i], d12 = rp1[ir];
    float d20 = rp2[il], d21 = rp2[i], d22 = rp2[ir];
    float c0 = ((float)il - cx) * ifx, c1 = ((float)i - cx) * ifx, c2 = ((float)ir - cx) * ifx;
    float w0 = ((float)r0 - cy) * ify, w1 = ((float)j - cy) * ify, w2 = ((float)r2 - cy) * ify;
    float dxx = -c0 * d00 + c2 * d02 - 2.f * (c0 * d10) + 2.f * (c2 * d12) - c0 * d20 + c2 * d22;
    float dxy = -w0 * d00 + w0 * d02 - 2.f * (w1 * d10) + 2.f * (w1 * d12) - w2 * d20 + w2 * d22;
    float dxz = -d00 + d02 - 2.f * d10 + 2.f * d12 - d20 + d22;
    float dyx = -c0 * d00 - 2.f * (c1 * d01) - c2 * d02 + c0 * d20 + 2.f * (c1 * d21) + c2 * d22;
    float dyy = -w0 * d00 - 2.f * (w0 * d01) - w0 * d02 + w2 * d20 + 2.f * (w2 * d21) + w2 * d22;
    float dyz = -d00 - 2.f * d01 - d02 + d20 + 2.f * d21 + d22;
    float nx = dxy * dyz - dxz * dyy;
    float ny = dxz * dyx - dxx * dyz;
    float nz = dxx * dyy - dxy * dyx;
    float inv = 1.f / (sqrtf(nx * nx + ny * ny + nz * nz) + 1e-8f);
    bool invalid = (d11 <= dmin) || (d11 >= dmax);
    float s = invalid ? 0.f : inv;
    h4 e;
    e[0] = (_Float16)d11;
    e[1] = (_Float16)(nx * s);
    e[2] = (_Float16)(ny * s);
    e[3] = (_Float16)(nz * s);
    nd[idx] = e;
}

// resid: 4 px/thread, ALL 8 gathers (2x16B per px) + 4 depth0 loads issued
// back-to-back for max memory-level parallelism, then packed-f16 bilinear.
__global__ __launch_bounds__(256, 4)
void k_resid(const float* __restrict__ depth0, const float* __restrict__ Kmat,
             const h4* __restrict__ nd, const float* __restrict__ pose,
             float* __restrict__ partials) {
    float fx = Kmat[0], cx = Kmat[2], fy = Kmat[4], cy = Kmat[5];
    float ifx = 1.f / fx, ify = 1.f / fy;
    float R00 = pose[0], R01 = pose[1], R02 = pose[2],  t0 = pose[3];
    float R10 = pose[4], R11 = pose[5], R12 = pose[6],  t1 = pose[7];
    float R20 = pose[8], R21 = pose[9], R22 = pose[10], t2 = pose[11];

#define ACC_DECL(i, n) float n = 0.f;
    ACC_LIST(ACC_DECL)
#undef ACC_DECL

    int tid = threadIdx.x;
    int wg = swz_bid(blockIdx.x, gridDim.x);
    int base = wg * 1024;                      // grid*1024 == NPIX exactly

    float d0s[4];
#pragma unroll
    for (int p = 0; p < 4; p++) d0s[p] = depth0[base + p * 256 + tid];  // coalesced

    float px[4], py[4], pz[4], wx[4], wy[4];
    int x0[4], y0[4];
    bool inview[4];
#pragma unroll
    for (int p = 0; p < 4; p++) {
        int idx = base + p * 256 + tid;
        int j = idx / W_IMG;
        int i = idx - j * W_IMG;
        float d0 = d0s[p];
        float cX = ((float)i - cx) * ifx;
        float cY = ((float)j - cy) * ify;
        float ax = R00 * cX + R01 * cY + R02;
        float ay = R10 * cX + R11 * cY + R12;
        float az = R20 * cX + R21 * cY + R22;
        float X = ax * d0 + t0;
        float Y = ay * d0 + t1;
        float Z = az * d0 + t2;
        float u, v; bool iv;
        if (Z > 1e-6f) {
            float rz = __builtin_amdgcn_rcpf(Z);
            u = X * rz * fx + cx;
            v = Y * rz * fy + cy;
            iv = (u > 0.f) && (u < (float)(W_IMG - 1)) && (v > 0.f) && (v < (float)(H_IMG - 1));
        } else { u = 0.f; v = 0.f; iv = false; }
        float x0f = floorf(u), y0f = floorf(v);
        x0[p] = (int)x0f; y0[p] = (int)y0f;
        wx[p] = u - x0f; wy[p] = v - y0f;
        px[p] = X; py[p] = Y; pz[p] = Z; inview[p] = iv;
    }
    // 8 gathers of 16 B, all independent, issued together
    h8 T[4], B[4];
    const h8 zz = {(_Float16)0.f, (_Float16)0.f, (_Float16)0.f, (_Float16)0.f,
                   (_Float16)0.f, (_Float16)0.f, (_Float16)0.f, (_Float16)0.f};
#pragma unroll
    for (int p = 0; p < 4; p++) {
        if (inview[p]) {
            size_t b00 = (size_t)(y0[p] * W_IMG + x0[p]);
            T[p] = *reinterpret_cast<const h8*>(nd + b00);          // row y0: rec(x0), rec(x0+1)
            B[p] = *reinterpret_cast<const h8*>(nd + b00 + W_IMG);  // row y0+1
        } else { T[p] = zz; B[p] = zz; }
    }
#pragma unroll
    for (int p = 0; p < 4; p++) {
        _Float16 hy = (_Float16)wy[p], h1y = (_Float16)(1.f - wy[p]);
        h8 vwy = {hy, hy, hy, hy, hy, hy, hy, hy};
        h8 v1y = {h1y, h1y, h1y, h1y, h1y, h1y, h1y, h1y};
        h8 V = T[p] * v1y + B[p] * vwy;        // {dv0,nx0,ny0,nz0, dv1,nx1,ny1,nz1}
        float w1x = 1.f - wx[p];
        float dv0 = (float)V[0], dv1 = (float)V[4];
        float rvz = dv0 * w1x + dv1 * wx[p];
        float rnx = (float)V[1] * w1x + (float)V[5] * wx[p];
        float rny = (float)V[2] * w1x + (float)V[6] * wx[p];
        float rnz = (float)V[3] * w1x + (float)V[7] * wx[p];
        float cX0 = ((float)x0[p] - cx) * ifx;
        float cY0 = ((float)y0[p] - cy) * ify;
        float rvx = cX0 * dv0 * w1x + (cX0 + ifx) * dv1 * wx[p];
        float dY0 = cY0 * (1.f - wy[p]), dY1 = (cY0 + ify) * wy[p];
        float d00 = (float)T[p][0], d01 = (float)T[p][4];
        float d10 = (float)B[p][0], d11 = (float)B[p][4];
        float rvy = (dY0 * d00 + dY1 * d10) * w1x + (dY0 * d01 + dY1 * d11) * wx[p];
        bool mask1 = rvz > 0.f;
        float ddx = px[p] - rvx, ddy = py[p] - rvy, ddz = pz[p] - rvz;
        float n2 = ddx * ddx + ddy * ddy + ddz * ddz;
        bool occ = (!inview[p]) || (n2 > 0.01f);
        bool bad = occ || !(d0s[p] > 0.f) || (!mask1);
        if (!bad) {
            float r = rnx * ddx + rny * ddy + rnz * ddz;
            float j0 = -(py[p] * rnz - pz[p] * rny);
            float j1 = -(pz[p] * rnx - px[p] * rnz);
            float j2 = -(px[p] * rny - py[p] * rnx);
            float j3 = -rnx, j4 = -rny, j5 = -rnz;
            s00 += j0 * j0; s01 += j0 * j1; s02 += j0 * j2; s03 += j0 * j3; s04 += j0 * j4; s05 += j0 * j5;
            s11 += j1 * j1; s12 += j1 * j2; s13 += j1 * j3; s14 += j1 * j4; s15 += j1 * j5;
            s22 += j2 * j2; s23 += j2 * j3; s24 += j2 * j4; s25 += j2 * j5;
            s33 += j3 * j3; s34 += j3 * j4; s35 += j3 * j5;
            s44 += j4 * j4; s45 += j4 * j5;
            s55 += j5 * j5;
            b0 += j0 * r; b1 += j1 * r; b2 += j2 * r;
            b3 += j3 * r; b4 += j4 * r; b5 += j5 * r;
        }
    }

    __shared__ float red[NACC][64];
    __shared__ float part2[NACC][8];
#define ACC_RED(i, n) { float v = n; v += __shfl_xor(v, 1); v += __shfl_xor(v, 2); \
                        if ((tid & 3) == 0) red[i][tid >> 2] = v; }
    ACC_LIST(ACC_RED)
#undef ACC_RED
    __syncthreads();
    if (tid < NACC * 8) {
        int k = tid >> 3, seg = tid & 7;
        const float4* row = reinterpret_cast<const float4*>(&red[k][seg * 8]);
        float4 a = row[0], b = row[1];
        part2[k][seg] = (a.x + a.y + a.z + a.w) + (b.x + b.y + b.z + b.w);
    }
    __syncthreads();
    if (tid < NACC) {
        float s = 0.f;
#pragma unroll
        for (int m = 0; m < 8; m++) s += part2[tid][m];
        partials[(size_t)tid * RB_REAL + blockIdx.x] = s;
    }
}

// 27 blocks: reduce + last-block GN solve (series trig for small angles).
__global__ __launch_bounds__(256)
void k_reduce_solve(const float* __restrict__ partials, double* __restrict__ sums,
                    unsigned int* __restrict__ counter, float* __restrict__ pose,
                    float* __restrict__ pose_out) {
    int k = blockIdx.x;
    int tid = threadIdx.x;
    double v = 0.0;
    for (int i = tid; i < RB_REAL; i += 256) v += (double)partials[(size_t)k * RB_REAL + i];
    for (int off = 32; off > 0; off >>= 1) v += __shfl_down(v, off);
    __shared__ double sw[4];
    __shared__ int amLast;
    int lane = tid & 63, wid = tid >> 6;
    if (lane == 0) sw[wid] = v;
    __syncthreads();
    if (tid == 0) {
        sums[k] = sw[0] + sw[1] + sw[2] + sw[3];
        __threadfence();
        unsigned int old = atomicAdd(counter, 1u);
        amLast = (old == NACC - 1) ? 1 : 0;
    }
    __syncthreads();
    if (!amLast) return;
    __threadfence();

    if (tid == 0) {
        double ssum[NACC];
        for (int q = 0; q < NACC; q++) ssum[q] = sums[q];
        double sM[6][7];
        int kk = 0;
        for (int a = 0; a < 6; a++)
            for (int c = a; c < 6; c++) {
                double s = ssum[kk++];
                sM[a][c] = s; sM[c][a] = s;
            }
        double tr = sM[0][0] + sM[1][1] + sM[2][2] + sM[3][3] + sM[4][4] + sM[5][5];
        for (int a = 0; a < 6; a++) sM[a][a] += tr * 0.001;
        for (int a = 0; a < 6; a++) sM[a][6] = ssum[21 + a];
        for (int c = 0; c < 6; c++) {
            int piv = c;
            double best = fabs(sM[c][c]);
            for (int r = c + 1; r < 6; r++) {
                double vv = fabs(sM[r][c]);
                if (vv > best) { best = vv; piv = r; }
            }
            if (piv != c)
                for (int q = c; q < 7; q++) { double t = sM[c][q]; sM[c][q] = sM[piv][q]; sM[piv][q] = t; }
            double pv = sM[c][c];
            for (int r = 0; r < 6; r++) {
                if (r == c) continue;
                double f = sM[r][c] / pv;
                for (int q = c; q < 7; q++) sM[r][q] -= f * sM[c][q];
            }
        }
        double xi0 = sM[0][6] / sM[0][0], xi1 = sM[1][6] / sM[1][1], xi2 = sM[2][6] / sM[2][2];
        double xi3 = sM[3][6] / sM[3][3], xi4 = sM[4][6] / sM[4][4], xi5 = sM[5][6] / sM[5][5];
        double th2 = xi0 * xi0 + xi1 * xi1 + xi2 * xi2;
        double th = sqrt(th2);
        double dR[3][3] = {{1, 0, 0}, {0, 1, 0}, {0, 0, 1}};
        if (th > 1e-10) {
            double sA, sB;
            if (th < 0.5) {  // Taylor: rel err < 1e-7 at th=0.5; avoids f64 trig libcalls
                double t4 = th2 * th2, t6 = t4 * th2;
                sA = 1.0 - th2 / 6.0 + t4 / 120.0 - t6 / 5040.0;
                sB = 0.5 - th2 / 24.0 + t4 / 720.0 - t6 / 40320.0;
            } else {
                sA = sin(th) / th;
                sB = (1.0 - cos(th)) / th2;
            }
            double wh[3][3] = {{0, -xi2, xi1}, {xi2, 0, -xi0}, {-xi1, xi0, 0}};
#pragma unroll
            for (int r = 0; r < 3; r++)
#pragma unroll
                for (int cc = 0; cc < 3; cc++) {
                    double w2 = 0;
#pragma unroll
                    for (int m = 0; m < 3; m++) w2 += wh[r][m] * wh[m][cc];
                    dR[r][cc] = (r == cc ? 1.0 : 0.0) + sA * wh[r][cc] + sB * w2;
                }
        }
        double R[3][3], t[3];
#pragma unroll
        for (int r = 0; r < 3; r++) {
#pragma unroll
            for (int cc = 0; cc < 3; cc++) R[r][cc] = pose[r * 4 + cc];
            t[r] = pose[r * 4 + 3];
        }
        double xt[3] = {xi3, xi4, xi5};
#pragma unroll
        for (int r = 0; r < 3; r++) {
#pragma unroll
            for (int cc = 0; cc < 3; cc++) {
                double s = 0;
#pragma unroll
                for (int m = 0; m < 3; m++) s += dR[r][m] * R[m][cc];
                pose[r * 4 + cc] = (float)s;
            }
            pose[r * 4 + 3] = (float)(dR[r][0] * t[0] + dR[r][1] * t[1] + dR[r][2] * t[2] + xt[r]);
        }
        *counter = 0u;
        for (int q = 0; q < 16; q++) pose_out[q] = pose[q];
    }
}

extern "C" void kernel_launch(void* const* d_in, const int* in_sizes, int n_in,
                              void* d_out, int out_size, void* d_ws, size_t ws_size,
                              hipStream_t stream) {
    const float* pose_in = (const float*)d_in[0];
    const float* depth0 = (const float*)d_in[1];
    const float* depth1 = (const float*)d_in[2];
    const float* K = (const float*)d_in[3];
    float* out = (float*)d_out;
    char* ws = (char*)d_ws;
    float* ws_pose = (float*)(ws + OFF_POSE);
    unsigned int* minmax = (unsigned int*)(ws + OFF_MINMAX);
    unsigned int* counter = (unsigned int*)(ws + OFF_COUNT);
    double* sums = (double*)(ws + OFF_SUMS);
    float* partials = (float*)(ws + OFF_PARTIALS);
    h4* nd = (h4*)(ws + OFF_ND);

    k_init<<<1, 64, 0, stream>>>(pose_in, ws_pose, minmax, counter);
    k_minmax<<<128, 256, 0, stream>>>((const float4*)depth1, minmax);
    k_nm<<<NB_NM, 256, 0, stream>>>(depth1, K, minmax, nd);
    for (int it = 0; it < 3; ++it) {
        k_resid<<<RB_REAL, 256, 0, stream>>>(depth0, K, nd, ws_pose, partials);
        k_reduce_solve<<<NACC, 256, 0, stream>>>(partials, sums, counter, ws_pose, out);
    }
}